// Round 1
// baseline (231.103 us; speedup 1.0000x reference)
//
#include <hip/hip_runtime.h>
#include <math.h>

#define NB 8192
#define ND 128
#define LDP 136  // 128 + 8 pad (16B) -> breaks 16-way LDS bank conflict down to 2-way (free)

typedef __bf16 bf16x8 __attribute__((ext_vector_type(8)));
typedef float f32x4 __attribute__((ext_vector_type(4)));

__device__ __forceinline__ unsigned short f2bf(float f) {
    union { float f; unsigned u; } v; v.f = f;
    unsigned r = v.u + 0x7FFFu + ((v.u >> 16) & 1u);  // RNE, inputs are finite
    return (unsigned short)(r >> 16);
}

// Kernel 1: per-row squared norms of sk and im; zero the rowsum accumulators.
__global__ void prep_kernel(const float* __restrict__ sk, const float* __restrict__ im,
                            float* __restrict__ rowsum, float* __restrict__ skn,
                            float* __restrict__ imn) {
    int i = blockIdx.x * blockDim.x + threadIdx.x;
    if (i >= NB) return;
    const float4* s = reinterpret_cast<const float4*>(sk + (size_t)i * ND);
    const float4* m = reinterpret_cast<const float4*>(im + (size_t)i * ND);
    float a = 0.f, b = 0.f;
#pragma unroll
    for (int k = 0; k < ND / 4; ++k) {
        float4 sv = s[k], mv = m[k];
        a += sv.x * sv.x + sv.y * sv.y + sv.z * sv.z + sv.w * sv.w;
        b += mv.x * mv.x + mv.y * mv.y + mv.z * mv.z + mv.w * mv.w;
    }
    skn[i] = a;
    imn[i] = b;
    rowsum[i] = 0.f;
}

// Kernel 2: 128x128 output tile per block; bf16 MFMA over K=128 (one LDS stage);
// fused epilogue: e = exp(-sqrt(max(skn+imn-2*dot,0))), per-row partial sums via
// shfl butterfly over the 16 column lanes + one atomicAdd per row per wave;
// diagonal distances written to diag[].
__global__ void __launch_bounds__(256) tile_kernel(
    const float* __restrict__ sk, const float* __restrict__ im,
    float* __restrict__ rowsum, float* __restrict__ diag,
    const float* __restrict__ skn, const float* __restrict__ imn) {
    __shared__ unsigned short As[128][LDP];
    __shared__ unsigned short Bs[128][LDP];

    const int tI = blockIdx.x * 128;
    const int tJ = blockIdx.y * 128;
    const int t = threadIdx.x;

    // Stage fp32 -> bf16 into LDS. Thread t loads 64 floats of row (t>>1),
    // half (t&1), for both sk and im tiles.
    {
        int row = t >> 1;
        int half = t & 1;
        const float4* gA = reinterpret_cast<const float4*>(sk + (size_t)(tI + row) * ND + half * 64);
        const float4* gB = reinterpret_cast<const float4*>(im + (size_t)(tJ + row) * ND + half * 64);
#pragma unroll
        for (int q = 0; q < 16; ++q) {
            float4 va = gA[q];
            ushort4 pa;
            pa.x = f2bf(va.x); pa.y = f2bf(va.y); pa.z = f2bf(va.z); pa.w = f2bf(va.w);
            *reinterpret_cast<ushort4*>(&As[row][half * 64 + q * 4]) = pa;
            float4 vb = gB[q];
            ushort4 pb;
            pb.x = f2bf(vb.x); pb.y = f2bf(vb.y); pb.z = f2bf(vb.z); pb.w = f2bf(vb.w);
            *reinterpret_cast<ushort4*>(&Bs[row][half * 64 + q * 4]) = pb;
        }
    }
    __syncthreads();

    const int wid = t >> 6, lane = t & 63;
    const int wr = wid >> 1, wc = wid & 1;   // wave owns 64x64 sub-tile
    const int hi = lane >> 4, lo = lane & 15;

    f32x4 acc[4][4];
#pragma unroll
    for (int m = 0; m < 4; ++m)
#pragma unroll
        for (int n = 0; n < 4; ++n)
            acc[m][n] = (f32x4){0.f, 0.f, 0.f, 0.f};

#pragma unroll
    for (int kk = 0; kk < 4; ++kk) {
        const int ko = kk * 32 + hi * 8;
        bf16x8 af[4], bfr[4];
#pragma unroll
        for (int m = 0; m < 4; ++m)
            af[m] = *reinterpret_cast<const bf16x8*>(&As[wr * 64 + m * 16 + lo][ko]);
#pragma unroll
        for (int n = 0; n < 4; ++n)
            bfr[n] = *reinterpret_cast<const bf16x8*>(&Bs[wc * 64 + n * 16 + lo][ko]);
#pragma unroll
        for (int m = 0; m < 4; ++m)
#pragma unroll
            for (int n = 0; n < 4; ++n)
                acc[m][n] = __builtin_amdgcn_mfma_f32_16x16x32_bf16(af[m], bfr[n], acc[m][n], 0, 0, 0);
    }

    // Epilogue. C/D layout: col = lane&15, row = (lane>>4)*4 + reg.
    float imn_v[4];
    int gj[4];
#pragma unroll
    for (int n = 0; n < 4; ++n) {
        gj[n] = tJ + wc * 64 + n * 16 + lo;
        imn_v[n] = imn[gj[n]];
    }
#pragma unroll
    for (int m = 0; m < 4; ++m) {
#pragma unroll
        for (int r = 0; r < 4; ++r) {
            const int gi = tI + wr * 64 + m * 16 + hi * 4 + r;
            const float sn = skn[gi];
            float rs = 0.f;
#pragma unroll
            for (int n = 0; n < 4; ++n) {
                float dot = acc[m][n][r];
                float sq = sn + imn_v[n] - 2.f * dot;
                float d = sqrtf(fmaxf(sq, 0.f));
                if (gi == gj[n]) diag[gi] = d;
                rs += __expf(-d);
            }
            // sum over the 16 column lanes (same hi, same row)
            rs += __shfl_xor(rs, 1);
            rs += __shfl_xor(rs, 2);
            rs += __shfl_xor(rs, 4);
            rs += __shfl_xor(rs, 8);
            if (lo == 0) atomicAdd(&rowsum[gi], rs);
        }
    }
}

// Kernel 3: loss = mean_i( log(rowsum[i]) + diag[i] )
__global__ void finalize_kernel(const float* __restrict__ rowsum,
                                const float* __restrict__ diag,
                                float* __restrict__ out) {
    __shared__ float red[256];
    float s = 0.f;
    for (int i = threadIdx.x; i < NB; i += 256)
        s += __logf(rowsum[i]) + diag[i];
    red[threadIdx.x] = s;
    __syncthreads();
    for (int st = 128; st > 0; st >>= 1) {
        if (threadIdx.x < st) red[threadIdx.x] += red[threadIdx.x + st];
        __syncthreads();
    }
    if (threadIdx.x == 0) out[0] = red[0] / (float)NB;
}

extern "C" void kernel_launch(void* const* d_in, const int* in_sizes, int n_in,
                              void* d_out, int out_size, void* d_ws, size_t ws_size,
                              hipStream_t stream) {
    const float* sk = (const float*)d_in[0];
    const float* im = (const float*)d_in[1];
    float* out = (float*)d_out;
    float* ws = (float*)d_ws;
    float* rowsum = ws;           // [NB]
    float* diag   = ws + NB;      // [NB]
    float* skn    = ws + 2 * NB;  // [NB]
    float* imn    = ws + 3 * NB;  // [NB]

    prep_kernel<<<NB / 256, 256, 0, stream>>>(sk, im, rowsum, skn, imn);
    dim3 grid(NB / 128, NB / 128);
    tile_kernel<<<grid, 256, 0, stream>>>(sk, im, rowsum, diag, skn, imn);
    finalize_kernel<<<1, 256, 0, stream>>>(rowsum, diag, out);
}

// Round 2
// 173.295 us; speedup vs baseline: 1.3336x; 1.3336x over previous
//
#include <hip/hip_runtime.h>
#include <math.h>

#define NB 8192
#define ND 128

typedef __bf16 bf16x8 __attribute__((ext_vector_type(8)));
typedef float f32x4 __attribute__((ext_vector_type(4)));

__device__ __forceinline__ unsigned short f2bf(float f) {
    union { float f; unsigned u; } v; v.f = f;
    unsigned r = v.u + 0x7FFFu + ((v.u >> 16) & 1u);  // RNE, inputs finite
    return (unsigned short)(r >> 16);
}

// Kernel 1: coalesced f32 -> bf16 conversion of both inputs into ws.
// 262144 float4 per array; first half of blocks do sk, second half im.
__global__ void convert_kernel(const float4* __restrict__ sk4, const float4* __restrict__ im4,
                               ushort4* __restrict__ skb4, ushort4* __restrict__ imb4) {
    int i = blockIdx.x * blockDim.x + threadIdx.x;        // 0 .. 524287
    const bool isIm = i >= (NB * ND / 4);
    int idx = i & (NB * ND / 4 - 1);
    float4 v = (isIm ? im4 : sk4)[idx];
    ushort4 p;
    p.x = f2bf(v.x); p.y = f2bf(v.y); p.z = f2bf(v.z); p.w = f2bf(v.w);
    (isIm ? imb4 : skb4)[idx] = p;
}

// Kernel 2: row squared norms (16 lanes per row, shfl reduce); zero rowsum.
__global__ void norm_kernel(const float* __restrict__ sk, const float* __restrict__ im,
                            float* __restrict__ skn, float* __restrict__ imn,
                            float* __restrict__ rowsum) {
    int gtid = blockIdx.x * blockDim.x + threadIdx.x;     // 0 .. 262143
    int row = gtid >> 4;                                  // 0 .. 16383
    int l16 = gtid & 15;
    int r = row & (NB - 1);
    const float* base = (row < NB ? sk : im) + (size_t)r * ND + l16 * 8;
    const float4 a = *reinterpret_cast<const float4*>(base);
    const float4 b = *reinterpret_cast<const float4*>(base + 4);
    float s = a.x * a.x + a.y * a.y + a.z * a.z + a.w * a.w
            + b.x * b.x + b.y * b.y + b.z * b.z + b.w * b.w;
    s += __shfl_xor(s, 1);
    s += __shfl_xor(s, 2);
    s += __shfl_xor(s, 4);
    s += __shfl_xor(s, 8);
    if (l16 == 0) {
        if (row < NB) { skn[r] = s; rowsum[r] = 0.f; }
        else          { imn[r] = s; }
    }
}

// Kernel 3: 128x128 output tile per block, NO LDS — MFMA fragments read
// directly from the bf16 arrays (L2/L3-resident). Fused epilogue:
// exp(-sqrt(max(skn+imn-2*dot,0))) row-summed via shfl + one atomic per row.
__global__ void __launch_bounds__(256) tile_kernel(
    const unsigned short* __restrict__ skb, const unsigned short* __restrict__ imb,
    const float* __restrict__ skn, const float* __restrict__ imn,
    float* __restrict__ rowsum, float* __restrict__ diag) {
    const int t = threadIdx.x;
    const int wid = t >> 6, lane = t & 63;
    const int wr = wid >> 1, wc = wid & 1;   // wave owns 64x64 sub-tile
    const int hi = lane >> 4, lo = lane & 15;
    const int tI = blockIdx.x * 128;
    const int tJ = blockIdx.y * 128;

    // A fragment (verified layout): lane row = lo, k-offset = hi*8.
    const unsigned short* Ab = skb + (size_t)(tI + wr * 64 + lo) * ND + hi * 8;
    const unsigned short* Bb = imb + (size_t)(tJ + wc * 64 + lo) * ND + hi * 8;

    f32x4 acc[4][4];
#pragma unroll
    for (int m = 0; m < 4; ++m)
#pragma unroll
        for (int n = 0; n < 4; ++n)
            acc[m][n] = (f32x4){0.f, 0.f, 0.f, 0.f};

#pragma unroll
    for (int kk = 0; kk < 4; ++kk) {
        bf16x8 af[4], bfr[4];
#pragma unroll
        for (int m = 0; m < 4; ++m)
            af[m] = *reinterpret_cast<const bf16x8*>(Ab + m * 16 * ND + kk * 32);
#pragma unroll
        for (int n = 0; n < 4; ++n)
            bfr[n] = *reinterpret_cast<const bf16x8*>(Bb + n * 16 * ND + kk * 32);
#pragma unroll
        for (int m = 0; m < 4; ++m)
#pragma unroll
            for (int n = 0; n < 4; ++n)
                acc[m][n] = __builtin_amdgcn_mfma_f32_16x16x32_bf16(af[m], bfr[n], acc[m][n], 0, 0, 0);
    }

    // Epilogue. C/D layout (verified): col = lane&15, row = (lane>>4)*4 + reg.
    float imn_v[4];
    int gj[4];
#pragma unroll
    for (int n = 0; n < 4; ++n) {
        gj[n] = tJ + wc * 64 + n * 16 + lo;
        imn_v[n] = imn[gj[n]];
    }
    const bool diagBlock = (tI == tJ);
#pragma unroll
    for (int m = 0; m < 4; ++m) {
#pragma unroll
        for (int r = 0; r < 4; ++r) {
            const int gi = tI + wr * 64 + m * 16 + hi * 4 + r;
            const float sn = skn[gi];
            float rs = 0.f;
#pragma unroll
            for (int n = 0; n < 4; ++n) {
                float sq = fmaf(-2.f, acc[m][n][r], sn + imn_v[n]);
                sq = fmaxf(sq, 0.f);
                float d;
                asm("v_sqrt_f32 %0, %1" : "=v"(d) : "v"(sq));
                if (diagBlock && gi == gj[n]) diag[gi] = d;
                float e, x = -1.442695041f * d;   // exp(-d) = 2^(-d*log2e)
                asm("v_exp_f32 %0, %1" : "=v"(e) : "v"(x));
                rs += e;
            }
            rs += __shfl_xor(rs, 1);
            rs += __shfl_xor(rs, 2);
            rs += __shfl_xor(rs, 4);
            rs += __shfl_xor(rs, 8);
            if (lo == 0) atomicAdd(&rowsum[gi], rs);
        }
    }
}

// Kernel 4: loss = mean_i( log(rowsum[i]) + diag[i] )
__global__ void finalize_kernel(const float* __restrict__ rowsum,
                                const float* __restrict__ diag,
                                float* __restrict__ out) {
    __shared__ float red[256];
    float s = 0.f;
    for (int i = threadIdx.x; i < NB; i += 256)
        s += __logf(rowsum[i]) + diag[i];
    red[threadIdx.x] = s;
    __syncthreads();
    for (int st = 128; st > 0; st >>= 1) {
        if (threadIdx.x < st) red[threadIdx.x] += red[threadIdx.x + st];
        __syncthreads();
    }
    if (threadIdx.x == 0) out[0] = red[0] / (float)NB;
}

extern "C" void kernel_launch(void* const* d_in, const int* in_sizes, int n_in,
                              void* d_out, int out_size, void* d_ws, size_t ws_size,
                              hipStream_t stream) {
    const float* sk = (const float*)d_in[0];
    const float* im = (const float*)d_in[1];
    float* out = (float*)d_out;
    float* ws = (float*)d_ws;
    float* rowsum = ws;            // [NB] f32
    float* diag   = ws + NB;       // [NB] f32
    float* skn    = ws + 2 * NB;   // [NB] f32
    float* imn    = ws + 3 * NB;   // [NB] f32
    unsigned short* skb = (unsigned short*)(ws + 4 * NB);  // [NB*ND] bf16
    unsigned short* imb = skb + (size_t)NB * ND;           // [NB*ND] bf16

    convert_kernel<<<2 * NB * ND / 4 / 256, 256, 0, stream>>>(
        (const float4*)sk, (const float4*)im, (ushort4*)skb, (ushort4*)imb);
    norm_kernel<<<2 * NB * 16 / 256, 256, 0, stream>>>(sk, im, skn, imn, rowsum);
    dim3 grid(NB / 128, NB / 128);
    tile_kernel<<<grid, 256, 0, stream>>>(skb, imb, skn, imn, rowsum, diag);
    finalize_kernel<<<1, 256, 0, stream>>>(rowsum, diag, out);
}

// Round 3
// 130.879 us; speedup vs baseline: 1.7658x; 1.3241x over previous
//
#include <hip/hip_runtime.h>
#include <math.h>

#define NB 8192
#define ND 128
#define NJB (NB / 128)   // 64 column-block partial rows

typedef __bf16 bf16x8 __attribute__((ext_vector_type(8)));
typedef float f32x4 __attribute__((ext_vector_type(4)));

__device__ __forceinline__ unsigned short f2bf(float f) {
    union { float f; unsigned u; } v; v.f = f;
    unsigned r = v.u + 0x7FFFu + ((v.u >> 16) & 1u);  // RNE, inputs finite
    return (unsigned short)(r >> 16);
}

// prep: 16 lanes per row. seg 0: convert sk + ||sk||^2; seg 1: convert im +
// ||im||^2; seg 2: diag[i] = ||sk_i - im_i|| in fp32 (more accurate than bf16 path).
__global__ void prep_kernel(const float* __restrict__ sk, const float* __restrict__ im,
                            ushort4* __restrict__ skb4, ushort4* __restrict__ imb4,
                            float* __restrict__ skn, float* __restrict__ imn,
                            float* __restrict__ diag) {
    int gtid = blockIdx.x * 256 + threadIdx.x;
    int row = gtid >> 4;
    int l16 = gtid & 15;
    int seg = row >> 13;          // NB == 2^13
    int r = row & (NB - 1);
    size_t off = (size_t)r * ND + l16 * 8;
    float s;
    if (seg == 2) {
        const float4* a4 = reinterpret_cast<const float4*>(sk + off);
        const float4* b4 = reinterpret_cast<const float4*>(im + off);
        float4 a0 = a4[0], a1 = a4[1], b0 = b4[0], b1 = b4[1];
        float d0 = a0.x - b0.x, d1 = a0.y - b0.y, d2 = a0.z - b0.z, d3 = a0.w - b0.w;
        float d4 = a1.x - b1.x, d5 = a1.y - b1.y, d6 = a1.z - b1.z, d7 = a1.w - b1.w;
        s = d0*d0 + d1*d1 + d2*d2 + d3*d3 + d4*d4 + d5*d5 + d6*d6 + d7*d7;
    } else {
        const float* src = (seg ? im : sk) + off;
        float4 a = *reinterpret_cast<const float4*>(src);
        float4 b = *reinterpret_cast<const float4*>(src + 4);
        s = a.x*a.x + a.y*a.y + a.z*a.z + a.w*a.w
          + b.x*b.x + b.y*b.y + b.z*b.z + b.w*b.w;
        ushort4 pa, pb;
        pa.x = f2bf(a.x); pa.y = f2bf(a.y); pa.z = f2bf(a.z); pa.w = f2bf(a.w);
        pb.x = f2bf(b.x); pb.y = f2bf(b.y); pb.z = f2bf(b.z); pb.w = f2bf(b.w);
        ushort4* dst = (seg ? imb4 : skb4) + (off >> 2);
        dst[0] = pa; dst[1] = pb;
    }
    s += __shfl_xor(s, 1);
    s += __shfl_xor(s, 2);
    s += __shfl_xor(s, 4);
    s += __shfl_xor(s, 8);
    if (l16 == 0) {
        if (seg == 0)      skn[r] = s;
        else if (seg == 1) imn[r] = s;
        else               diag[r] = sqrtf(s);
    }
}

// tile: 128x128 per block, swapped operands (A=im rows j, B=sk rows i) so the
// j-sum is lane-local. One-step load-ahead pipeline. No atomics: LDS-combine
// the two j-half waves, store one partial row per (block, j-chunk).
__global__ void __launch_bounds__(256) tile_kernel(
    const unsigned short* __restrict__ skb, const unsigned short* __restrict__ imb,
    const float* __restrict__ skn, const float* __restrict__ imn,
    float* __restrict__ partial) {
    __shared__ float lds_part[2][128];
    const int t = threadIdx.x;
    const int wid = t >> 6, lane = t & 63;
    const int wr = wid >> 1, wc = wid & 1;   // wr: j-half, wc: i-half
    const int hi = lane >> 4, lo = lane & 15;
    const int tI = blockIdx.x * 128;         // sk (i) base
    const int tJ = blockIdx.y * 128;         // im (j) base
    const int ibase = tI + wc * 64;
    const int jbase = tJ + wr * 64;

    const unsigned short* Ab = imb + (size_t)(jbase + lo) * ND + hi * 8;
    const unsigned short* Bb = skb + (size_t)(ibase + lo) * ND + hi * 8;

    f32x4 acc[4][4];   // acc[m][n]: j = jbase+m*16+hi*4+r, i = ibase+n*16+lo
#pragma unroll
    for (int m = 0; m < 4; ++m)
#pragma unroll
        for (int n = 0; n < 4; ++n)
            acc[m][n] = (f32x4){0.f, 0.f, 0.f, 0.f};

    bf16x8 af[2][4], bfr[2][4];
#pragma unroll
    for (int m = 0; m < 4; ++m) {
        af[0][m]  = *reinterpret_cast<const bf16x8*>(Ab + (size_t)m * 16 * ND);
        bfr[0][m] = *reinterpret_cast<const bf16x8*>(Bb + (size_t)m * 16 * ND);
    }
#pragma unroll
    for (int kk = 0; kk < 4; ++kk) {
        if (kk < 3) {
#pragma unroll
            for (int m = 0; m < 4; ++m) {
                af[(kk + 1) & 1][m]  = *reinterpret_cast<const bf16x8*>(Ab + (size_t)m * 16 * ND + (kk + 1) * 32);
                bfr[(kk + 1) & 1][m] = *reinterpret_cast<const bf16x8*>(Bb + (size_t)m * 16 * ND + (kk + 1) * 32);
            }
        }
#pragma unroll
        for (int m = 0; m < 4; ++m)
#pragma unroll
            for (int n = 0; n < 4; ++n)
                acc[m][n] = __builtin_amdgcn_mfma_f32_16x16x32_bf16(af[kk & 1][m], bfr[kk & 1][n], acc[m][n], 0, 0, 0);
    }

    // Epilogue: per lane, i is fixed (per n), j varies over (m, r).
    float imnv[4][4];
#pragma unroll
    for (int m = 0; m < 4; ++m) {
        float4 v = *reinterpret_cast<const float4*>(imn + jbase + m * 16 + hi * 4);
        imnv[m][0] = v.x; imnv[m][1] = v.y; imnv[m][2] = v.z; imnv[m][3] = v.w;
    }
#pragma unroll
    for (int n = 0; n < 4; ++n) {
        const float skv = skn[ibase + n * 16 + lo];
        float sr[4] = {0.f, 0.f, 0.f, 0.f};
#pragma unroll
        for (int m = 0; m < 4; ++m) {
#pragma unroll
            for (int r = 0; r < 4; ++r) {
                float sq = fmaf(-2.f, acc[m][n][r], skv + imnv[m][r]);
                sq = fmaxf(sq, 0.f);
                float d;
                asm("v_sqrt_f32 %0, %1" : "=v"(d) : "v"(sq));
                float x = -1.442695041f * d;   // exp(-d) = 2^(-d*log2e)
                float e;
                asm("v_exp_f32 %0, %1" : "=v"(e) : "v"(x));
                sr[r] += e;
            }
        }
        float s = (sr[0] + sr[1]) + (sr[2] + sr[3]);  // 64-j partial for lane's i
        s += __shfl_xor(s, 16);
        s += __shfl_xor(s, 32);
        if (lane < 16) lds_part[wr][wc * 64 + n * 16 + lane] = s;
    }
    __syncthreads();
    if (t < 128) {
        float v = lds_part[0][t] + lds_part[1][t];
        partial[(size_t)blockIdx.y * NB + tI + t] = v;
    }
}

// rowsum: one thread per row i; sum the 64 partials, v = log(rs) + diag[i];
// block-reduce to blocksum.
__global__ void rowsum_kernel(const float* __restrict__ partial,
                              const float* __restrict__ diag,
                              float* __restrict__ blocksum) {
    const int i = blockIdx.x * 256 + threadIdx.x;
    float rs = 0.f;
#pragma unroll 8
    for (int c = 0; c < NJB; ++c) rs += partial[(size_t)c * NB + i];
    float v = __logf(rs) + diag[i];
    __shared__ float red[256];
    red[threadIdx.x] = v;
    __syncthreads();
    for (int st = 128; st > 0; st >>= 1) {
        if (threadIdx.x < st) red[threadIdx.x] += red[threadIdx.x + st];
        __syncthreads();
    }
    if (threadIdx.x == 0) blocksum[blockIdx.x] = red[0];
}

// final: single wave sums the 32 block sums.
__global__ void final_kernel(const float* __restrict__ blocksum, float* __restrict__ out) {
    float s = (threadIdx.x < NB / 256) ? blocksum[threadIdx.x] : 0.f;
    s += __shfl_xor(s, 1);
    s += __shfl_xor(s, 2);
    s += __shfl_xor(s, 4);
    s += __shfl_xor(s, 8);
    s += __shfl_xor(s, 16);
    s += __shfl_xor(s, 32);
    if (threadIdx.x == 0) out[0] = s / (float)NB;
}

extern "C" void kernel_launch(void* const* d_in, const int* in_sizes, int n_in,
                              void* d_out, int out_size, void* d_ws, size_t ws_size,
                              hipStream_t stream) {
    const float* sk = (const float*)d_in[0];
    const float* im = (const float*)d_in[1];
    float* out = (float*)d_out;
    float* ws = (float*)d_ws;

    unsigned short* skb = (unsigned short*)ws;              // NB*ND bf16 (2 MB)
    unsigned short* imb = skb + (size_t)NB * ND;            // NB*ND bf16 (2 MB)
    float* fbase   = ws + (size_t)NB * ND;                  // 4 MB consumed above
    float* skn     = fbase;                                 // [NB]
    float* imn     = fbase + NB;                            // [NB]
    float* diag    = fbase + 2 * NB;                        // [NB]
    float* partial = fbase + 3 * NB;                        // [NJB][NB] (2 MB)
    float* blocksum = partial + (size_t)NJB * NB;           // [32]

    prep_kernel<<<3 * NB * 16 / 256, 256, 0, stream>>>(
        sk, im, (ushort4*)skb, (ushort4*)imb, skn, imn, diag);
    dim3 grid(NB / 128, NB / 128);
    tile_kernel<<<grid, 256, 0, stream>>>(skb, imb, skn, imn, partial);
    rowsum_kernel<<<NB / 256, 256, 0, stream>>>(partial, diag, blocksum);
    final_kernel<<<1, 64, 0, stream>>>(blocksum, out);
}